// Round 1
// baseline (551.184 us; speedup 1.0000x reference)
//
#include <hip/hip_runtime.h>

// Problem constants (fixed by setup_inputs)
constexpr int B        = 128;
constexpr int IN_CAPS  = 1152;
constexpr int OUT_CAPS = 32;
constexpr int IN_D     = 8;
constexpr int OUT_D    = 16;
constexpr int ITERS    = 3;

constexpr int THREADS = 384;             // 6 waves
constexpr int NW      = THREADS / 64;    // 6
constexpr int IPT     = IN_CAPS / THREADS; // 3 in-caps per thread

// One block per (b, j). u_hat[b, :, j, :] lives in registers distributed
// across threads (thread t owns i = 3t..3t+2, 48 floats). The whole
// 3-iteration routing loop is internal to the block: only 16-float block
// reductions (s) and scalar reductions (softmax max/sum) cross threads.
__global__ __launch_bounds__(THREADS) void caps_route(
    const float* __restrict__ u,   // [B, IN_CAPS, IN_D]
    const float* __restrict__ w,   // [IN_CAPS, OUT_CAPS, IN_D, OUT_D]
    float* __restrict__ out)       // [B, OUT_CAPS, OUT_D]
{
    // Bijective XCD swizzle: work ids are j-major (128 consecutive ids share
    // one j). Hardware round-robins blockIdx across 8 XCDs; remap so each XCD
    // gets a contiguous chunk of work ids -> 4 j-slices (2.3 MB weight) per
    // XCD L2 instead of all 32 (18.9 MB).
    const int nwg = gridDim.x;            // 4096, divisible by 8
    const int h   = blockIdx.x;
    const int wid = (h & 7) * (nwg >> 3) + (h >> 3);
    const int j   = wid / B;              // 0..31
    const int b   = wid % B;              // 0..127

    const int t    = threadIdx.x;
    const int lane = t & 63;
    const int wv   = t >> 6;

    __shared__ float lds_m[NW * OUT_D];   // per-wave partials for s[16]
    __shared__ float lds_s[NW];           // per-wave scalar partials

    // ---- Step 1: u_hat for my 3 i's, into registers --------------------
    float uh[IPT][OUT_D];
    const int i0 = t * IPT;
    {
        // u[b, i0 .. i0+2, :] : 24 contiguous floats
        float uv[IPT][IN_D];
        const float* up = u + ((size_t)b * IN_CAPS + i0) * IN_D;
        #pragma unroll
        for (int q = 0; q < IPT * IN_D; q += 4) {
            float4 t4 = *reinterpret_cast<const float4*>(up + q);
            uv[q / IN_D][q % IN_D]           = t4.x;
            uv[(q + 1) / IN_D][(q + 1) % IN_D] = t4.y;
            uv[(q + 2) / IN_D][(q + 2) % IN_D] = t4.z;
            uv[(q + 3) / IN_D][(q + 3) % IN_D] = t4.w;
        }
        #pragma unroll
        for (int k = 0; k < IPT; ++k) {
            const int i = i0 + k;
            const float* wp = w + (((size_t)i * OUT_CAPS + j) * IN_D) * OUT_D;
            #pragma unroll
            for (int m = 0; m < OUT_D; ++m) uh[k][m] = 0.0f;
            #pragma unroll
            for (int n = 0; n < IN_D; ++n) {
                #pragma unroll
                for (int m = 0; m < OUT_D; m += 4) {
                    float4 w4 = *reinterpret_cast<const float4*>(wp + n * OUT_D + m);
                    uh[k][m + 0] = fmaf(w4.x, uv[k][n], uh[k][m + 0]);
                    uh[k][m + 1] = fmaf(w4.y, uv[k][n], uh[k][m + 1]);
                    uh[k][m + 2] = fmaf(w4.z, uv[k][n], uh[k][m + 2]);
                    uh[k][m + 3] = fmaf(w4.w, uv[k][n], uh[k][m + 3]);
                }
            }
        }
    }

    // ---- Step 2: routing iterations ------------------------------------
    float blog[IPT];
    #pragma unroll
    for (int k = 0; k < IPT; ++k) blog[k] = 0.0f;

    float v[OUT_D];

    for (int it = 0; it < ITERS; ++it) {
        // softmax over i (1152 values spread across block)
        float mx = blog[0];
        #pragma unroll
        for (int k = 1; k < IPT; ++k) mx = fmaxf(mx, blog[k]);
        #pragma unroll
        for (int d = 1; d < 64; d <<= 1) mx = fmaxf(mx, __shfl_xor(mx, d));
        if (lane == 0) lds_s[wv] = mx;
        __syncthreads();
        float gmx = lds_s[0];
        #pragma unroll
        for (int q = 1; q < NW; ++q) gmx = fmaxf(gmx, lds_s[q]);
        __syncthreads();  // all reads of lds_s done before rewrite

        float e[IPT];
        float esum = 0.0f;
        #pragma unroll
        for (int k = 0; k < IPT; ++k) { e[k] = __expf(blog[k] - gmx); esum += e[k]; }
        #pragma unroll
        for (int d = 1; d < 64; d <<= 1) esum += __shfl_xor(esum, d);
        if (lane == 0) lds_s[wv] = esum;
        __syncthreads();
        float gsum = 0.0f;
        #pragma unroll
        for (int q = 0; q < NW; ++q) gsum += lds_s[q];
        const float cinv = 1.0f / gsum;   // c_i = e_i * cinv

        // s[m] = cinv * sum_i e_i * uh[i][m]
        float sp[OUT_D];
        #pragma unroll
        for (int m = 0; m < OUT_D; ++m) sp[m] = 0.0f;
        #pragma unroll
        for (int k = 0; k < IPT; ++k)
            #pragma unroll
            for (int m = 0; m < OUT_D; ++m)
                sp[m] = fmaf(e[k], uh[k][m], sp[m]);
        #pragma unroll
        for (int m = 0; m < OUT_D; ++m)
            #pragma unroll
            for (int d = 1; d < 64; d <<= 1)
                sp[m] += __shfl_xor(sp[m], d);
        if (lane == 0) {
            #pragma unroll
            for (int m = 0; m < OUT_D; ++m) lds_m[wv * OUT_D + m] = sp[m];
        }
        __syncthreads();
        float s[OUT_D];
        #pragma unroll
        for (int m = 0; m < OUT_D; ++m) {
            float acc = 0.0f;
            #pragma unroll
            for (int q = 0; q < NW; ++q) acc += lds_m[q * OUT_D + m];
            s[m] = acc * cinv;
        }
        __syncthreads();  // lds_m/lds_s reads done before next iteration writes

        // squash
        float s2 = 0.0f;
        #pragma unroll
        for (int m = 0; m < OUT_D; ++m) s2 = fmaf(s[m], s[m], s2);
        const float scale = (s2 / (1.0f + s2)) * rsqrtf(s2 + 1e-8f);
        #pragma unroll
        for (int m = 0; m < OUT_D; ++m) v[m] = s[m] * scale;

        // logit update (skip on last iteration: a/b unused by output)
        if (it < ITERS - 1) {
            #pragma unroll
            for (int k = 0; k < IPT; ++k) {
                float a = 0.0f;
                #pragma unroll
                for (int m = 0; m < OUT_D; ++m) a = fmaf(v[m], uh[k][m], a);
                blog[k] += a;
            }
        }
    }

    // ---- Step 3: write v[b, j, :] ---------------------------------------
    if (t < OUT_D)
        out[((size_t)b * OUT_CAPS + j) * OUT_D + t] = v[t];
}

extern "C" void kernel_launch(void* const* d_in, const int* in_sizes, int n_in,
                              void* d_out, int out_size, void* d_ws, size_t ws_size,
                              hipStream_t stream) {
    const float* u = (const float*)d_in[0];   // [128, 1152, 8]
    const float* w = (const float*)d_in[1];   // [1152, 32, 8, 16]
    float* out     = (float*)d_out;           // [128, 32, 16]
    (void)in_sizes; (void)n_in; (void)out_size; (void)d_ws; (void)ws_size;

    dim3 grid(B * OUT_CAPS);   // 4096 blocks, one per (b, j)
    dim3 block(THREADS);       // 384 threads = 6 waves
    hipLaunchKernelGGL(caps_route, grid, block, 0, stream, u, w, out);
}

// Round 2
// 537.937 us; speedup vs baseline: 1.0246x; 1.0246x over previous
//
#include <hip/hip_runtime.h>
#include <stdint.h>

// Problem constants (fixed by setup_inputs)
constexpr int B_SZ     = 128;
constexpr int IN_CAPS  = 1152;
constexpr int OUT_CAPS = 32;
constexpr int IN_D     = 8;
constexpr int OUT_D    = 16;
constexpr int ITERS    = 3;

constexpr int THREADS = 384;              // 6 waves
constexpr int NW      = THREADS / 64;     // 6
constexpr int G       = 2;                // batches per block (weight reuse)
constexpr int TILE_I  = THREADS / G;      // 192 i-rows per LDS tile
constexpr int NTILE   = IN_CAPS / TILE_I; // 6
constexpr int ROW_U32 = 64;               // 128 bf16 per row = 64 dwords
constexpr int W_ISTRIDE = OUT_CAPS * IN_D * OUT_D; // 4096 floats between i's

// One block per (j, batch-pair). Weight column w[:,j,:,:] is staged through
// LDS in 192-i tiles as bf16 (48 KB -> 2 blocks/CU). Thread t owns batch
// bl=t&1 and row ir=t>>1 of each tile; u_hat lives in registers uh[6][16]
// (static indexing only). Routing loop is shfl + tiny LDS reductions.
__global__ __launch_bounds__(THREADS, 3) void caps_route(
    const float* __restrict__ u,   // [B, IN_CAPS, IN_D]
    const float* __restrict__ w,   // [IN_CAPS, OUT_CAPS, IN_D, OUT_D]
    float* __restrict__ out)       // [B, OUT_CAPS, OUT_D]
{
    __shared__ uint32_t tile[TILE_I * ROW_U32];     // 48 KB bf16 weight tile
    __shared__ float red_s[NW * G];                 // scalar reduction scratch
    __shared__ float red_m[NW * G * OUT_D];         // s[16] reduction scratch

    // Bijective XCD swizzle (2048 % 8 == 0): j-major work ids so each XCD's
    // L2 holds 4 j-columns (4 x 589 KB = 2.3 MB < 4 MB).
    const int nwg = gridDim.x;                       // 2048
    const int bid = blockIdx.x;
    const int wid = (bid & 7) * (nwg >> 3) + (bid >> 3);
    const int j   = wid >> 6;                        // 0..31
    const int b0  = (wid & 63) * G;                  // 0..126 step 2

    const int tid  = threadIdx.x;
    const int bl   = tid & 1;                        // my batch within pair
    const int ir   = tid >> 1;                       // my row in tile, 0..191
    const int wv   = tid >> 6;
    const int lane = tid & 63;
    const int swz  = ir & 7;
    const int b    = b0 + bl;

    const float* wj = w + (size_t)j * (IN_D * OUT_D);  // + i*4096 + c

    float uh[NTILE][OUT_D];   // 96 VGPRs, static indexing (loops unrolled)

    // ================= Phase 1: u_hat into registers =================
    #pragma unroll
    for (int r = 0; r < NTILE; ++r) {
        __syncthreads();   // previous tile's reads complete before overwrite
        // ---- stage: 96 KB f32 -> 48 KB bf16, XOR-swizzled octets ----
        #pragma unroll
        for (int q = 0; q < 16; ++q) {
            const int f4  = q * THREADS + tid;   // float4 index, 0..6143
            const int row = f4 >> 5;             // 0..191 (32 float4 per row)
            const int c4  = f4 & 31;             // float4 within row
            const float4 s4 = *reinterpret_cast<const float4*>(
                wj + (size_t)(r * TILE_I + row) * W_ISTRIDE + c4 * 4);
            uint32_t p0, p1;
            asm("v_cvt_pk_bf16_f32 %0, %1, %2" : "=v"(p0) : "v"(s4.x), "v"(s4.y));
            asm("v_cvt_pk_bf16_f32 %0, %1, %2" : "=v"(p1) : "v"(s4.z), "v"(s4.w));
            const int o = c4 >> 1, h = c4 & 1;   // octet (16B) and half
            const int dst = row * ROW_U32 + ((o ^ (row & 7)) << 2) + (h << 1);
            *reinterpret_cast<uint2*>(&tile[dst]) = make_uint2(p0, p1);
        }
        __syncthreads();
        // ---- compute uh[r][:] for my (i, b) ----
        const int ig = r * TILE_I + ir;
        const float4 ua = *reinterpret_cast<const float4*>(
            u + ((size_t)b * IN_CAPS + ig) * IN_D);
        const float4 ub = *reinterpret_cast<const float4*>(
            u + ((size_t)b * IN_CAPS + ig) * IN_D + 4);
        const float un[8] = {ua.x, ua.y, ua.z, ua.w, ub.x, ub.y, ub.z, ub.w};
        #pragma unroll
        for (int m = 0; m < OUT_D; ++m) uh[r][m] = 0.0f;
        #pragma unroll
        for (int n = 0; n < IN_D; ++n) {
            #pragma unroll
            for (int h = 0; h < 2; ++h) {
                const int o = 2 * n + h;     // octet: c = 16n + 8h + [0,8)
                const uint4 rd = *reinterpret_cast<const uint4*>(
                    &tile[ir * ROW_U32 + ((o ^ swz) << 2)]);
                const uint32_t dw[4] = {rd.x, rd.y, rd.z, rd.w};
                #pragma unroll
                for (int k = 0; k < 4; ++k) {
                    const float wlo = __uint_as_float(dw[k] << 16);
                    const float whi = __uint_as_float(dw[k] & 0xffff0000u);
                    uh[r][8*h + 2*k]     = fmaf(un[n], wlo, uh[r][8*h + 2*k]);
                    uh[r][8*h + 2*k + 1] = fmaf(un[n], whi, uh[r][8*h + 2*k + 1]);
                }
            }
        }
    }

    // ================= Phase 2: routing iterations =================
    float blog[NTILE];
    #pragma unroll
    for (int r = 0; r < NTILE; ++r) blog[r] = 0.0f;
    float vv[OUT_D];

    for (int it = 0; it < ITERS; ++it) {
        // softmax denominator over i for my b (no max-sub: |logit| <~ 60,
        // exp fits f32 comfortably; iter 0 is exp(0)=1 exactly)
        float e[NTILE];
        float esum = 0.0f;
        #pragma unroll
        for (int r = 0; r < NTILE; ++r) { e[r] = __expf(blog[r]); esum += e[r]; }
        #pragma unroll
        for (int msk = 2; msk <= 32; msk <<= 1) esum += __shfl_xor(esum, msk);
        if (lane < G) red_s[wv * G + lane] = esum;   // lane==bl here
        __syncthreads();
        float gsum = 0.0f;
        #pragma unroll
        for (int q = 0; q < NW; ++q) gsum += red_s[q * G + bl];
        const float cinv = 1.0f / gsum;

        // s[m] = cinv * sum_i e_i * uh[i][m]  (reduce over same-b lanes)
        float sp[OUT_D];
        #pragma unroll
        for (int m = 0; m < OUT_D; ++m) sp[m] = 0.0f;
        #pragma unroll
        for (int r = 0; r < NTILE; ++r)
            #pragma unroll
            for (int m = 0; m < OUT_D; ++m)
                sp[m] = fmaf(e[r], uh[r][m], sp[m]);
        #pragma unroll
        for (int msk = 2; msk <= 32; msk <<= 1)
            #pragma unroll
            for (int m = 0; m < OUT_D; ++m)
                sp[m] += __shfl_xor(sp[m], msk);
        if (lane < G) {
            #pragma unroll
            for (int m = 0; m < OUT_D; ++m)
                red_m[(wv * G + lane) * OUT_D + m] = sp[m];
        }
        __syncthreads();
        float s2 = 0.0f;
        #pragma unroll
        for (int m = 0; m < OUT_D; ++m) {
            float acc = 0.0f;
            #pragma unroll
            for (int q = 0; q < NW; ++q) acc += red_m[(q * G + bl) * OUT_D + m];
            const float sm = acc * cinv;
            vv[m] = sm;
            s2 = fmaf(sm, sm, s2);
        }
        const float scale = (s2 / (1.0f + s2)) * rsqrtf(s2 + 1e-8f);
        #pragma unroll
        for (int m = 0; m < OUT_D; ++m) vv[m] *= scale;

        // logit update (skip on last iteration; disjoint red_s/red_m arrays
        // + the two barriers above make cross-iteration reuse race-free)
        if (it < ITERS - 1) {
            #pragma unroll
            for (int r = 0; r < NTILE; ++r) {
                float a = 0.0f;
                #pragma unroll
                for (int m = 0; m < OUT_D; ++m) a = fmaf(vv[m], uh[r][m], a);
                blog[r] += a;
            }
        }
    }

    // ================= Phase 3: write v[b0..b0+1, j, :] =================
    if (tid < G) {   // thread 0 holds b0's v, thread 1 holds b0+1's
        float4* op = reinterpret_cast<float4*>(
            out + ((size_t)(b0 + tid) * OUT_CAPS + j) * OUT_D);
        op[0] = make_float4(vv[0],  vv[1],  vv[2],  vv[3]);
        op[1] = make_float4(vv[4],  vv[5],  vv[6],  vv[7]);
        op[2] = make_float4(vv[8],  vv[9],  vv[10], vv[11]);
        op[3] = make_float4(vv[12], vv[13], vv[14], vv[15]);
    }
}

extern "C" void kernel_launch(void* const* d_in, const int* in_sizes, int n_in,
                              void* d_out, int out_size, void* d_ws, size_t ws_size,
                              hipStream_t stream) {
    const float* u = (const float*)d_in[0];   // [128, 1152, 8]
    const float* w = (const float*)d_in[1];   // [1152, 32, 8, 16]
    float* out     = (float*)d_out;           // [128, 32, 16]
    (void)in_sizes; (void)n_in; (void)out_size; (void)d_ws; (void)ws_size;

    dim3 grid(OUT_CAPS * (B_SZ / G));   // 32 j x 64 batch-pairs = 2048 blocks
    dim3 block(THREADS);                // 384 threads = 6 waves
    hipLaunchKernelGGL(caps_route, grid, block, 0, stream, u, w, out);
}

// Round 3
// 270.585 us; speedup vs baseline: 2.0370x; 1.9881x over previous
//
#include <hip/hip_runtime.h>
#include <stdint.h>

// Problem constants (fixed by setup_inputs)
constexpr int B_SZ     = 128;
constexpr int IN_CAPS  = 1152;
constexpr int OUT_CAPS = 32;
constexpr int IN_D     = 8;
constexpr int OUT_D    = 16;
constexpr int ITERS    = 3;

constexpr int THREADS  = 768;               // 12 waves
constexpr int NW       = THREADS / 64;      // 12
constexpr int G        = 2;                 // batches per block
constexpr int TILE_R   = 192;               // i-rows per LDS tile
constexpr int NTILE    = IN_CAPS / TILE_R;  // 6
constexpr int ROW_U32  = 64;                // 128 bf16 = 256 B per row
constexpr int W_ISTRIDE = OUT_CAPS * IN_D * OUT_D;  // 4096 floats between i's

// One block per (j, batch-pair). Thread owns (bl = which batch, mh = which
// half of m, ir = i-row within tile): uh[6][8] = 48 VGPRs. Weight column
// w[:,j,:,:] streams through double-buffered bf16 LDS tiles (2 x 48 KB);
// next tile's global loads are issued before current tile's compute so HBM/L2
// latency hides under the 8x16-FMA inner loop. NO second launch_bounds arg:
// R2's (384,3) capped VGPRs at 84 and spilled 400 MB of scratch.
__global__ __launch_bounds__(THREADS) void caps_route(
    const float* __restrict__ u,   // [B, IN_CAPS, IN_D]
    const float* __restrict__ w,   // [IN_CAPS, OUT_CAPS, IN_D, OUT_D]
    float* __restrict__ out)       // [B, OUT_CAPS, OUT_D]
{
    __shared__ __align__(16) uint32_t tile[2][TILE_R * ROW_U32]; // 96 KB
    __shared__ float red_s[NW * 4];          // esum partials per (wave,bl,mh)
    __shared__ float red_m[NW * 4 * 8];      // s[8] partials
    __shared__ float red_s2[4];              // s^2 halves exchange

    // Bijective XCD swizzle (2048 % 8 == 0): j-major ids -> each XCD's L2
    // holds 4 j-columns (2.3 MB) across all its blocks/rounds.
    const int nwg = gridDim.x;               // 2048
    const int bid = blockIdx.x;
    const int wid = (bid & 7) * (nwg >> 3) + (bid >> 3);
    const int j   = wid >> 6;                // 0..31
    const int b0  = (wid & 63) * G;          // 0..126 step 2

    const int tid  = threadIdx.x;
    const int bl   = tid & 1;                // batch within pair
    const int mh   = (tid >> 1) & 1;         // m-half (m = mh*8 + k)
    const int ir   = tid >> 2;               // i-row in tile, 0..191
    const int wv   = tid >> 6;               // wave 0..11
    const int lane = tid & 63;
    const int b    = b0 + bl;
    const int sz   = ir & 15;                // read-side swizzle

    // staging mapping: float4 index f4 = q*768+tid -> row, col
    const int srow = tid >> 5;               // 0..23
    const int sc4  = tid & 31;               // float4 within row
    const int so   = sc4 >> 1;               // 16B slot 0..15
    const int sh   = sc4 & 1;                // half of slot

    const float* wj = w + (size_t)j * (IN_D * OUT_D);

    float uh[NTILE][8];                      // 48 VGPRs, static indexing
    float unbuf[2][8];                       // u for current/next tile
    float4 stg[8];                           // in-flight weight float4s

    // ---- prologue: stage tile 0 ----
    #pragma unroll
    for (int q = 0; q < 8; ++q)
        stg[q] = *reinterpret_cast<const float4*>(
            wj + (size_t)(q * 24 + srow) * W_ISTRIDE + sc4 * 4);
    {
        const float4 ua = *reinterpret_cast<const float4*>(
            u + ((size_t)b * IN_CAPS + ir) * IN_D);
        const float4 ub = *reinterpret_cast<const float4*>(
            u + ((size_t)b * IN_CAPS + ir) * IN_D + 4);
        unbuf[0][0]=ua.x; unbuf[0][1]=ua.y; unbuf[0][2]=ua.z; unbuf[0][3]=ua.w;
        unbuf[0][4]=ub.x; unbuf[0][5]=ub.y; unbuf[0][6]=ub.z; unbuf[0][7]=ub.w;
    }
    #pragma unroll
    for (int q = 0; q < 8; ++q) {
        const int row = q * 24 + srow;
        uint32_t p0, p1;
        asm("v_cvt_pk_bf16_f32 %0, %1, %2" : "=v"(p0) : "v"(stg[q].x), "v"(stg[q].y));
        asm("v_cvt_pk_bf16_f32 %0, %1, %2" : "=v"(p1) : "v"(stg[q].z), "v"(stg[q].w));
        *reinterpret_cast<uint2*>(
            &tile[0][row * ROW_U32 + ((so ^ (row & 15)) << 2) + (sh << 1)]) =
            make_uint2(p0, p1);
    }
    __syncthreads();

    // ---- main tile loop: issue(t+1) | compute(t) | commit(t+1) ----
    #pragma unroll
    for (int t = 0; t < NTILE; ++t) {
        if (t < NTILE - 1) {
            #pragma unroll
            for (int q = 0; q < 8; ++q)
                stg[q] = *reinterpret_cast<const float4*>(
                    wj + (size_t)((t + 1) * TILE_R + q * 24 + srow) * W_ISTRIDE + sc4 * 4);
            const float4 ua = *reinterpret_cast<const float4*>(
                u + ((size_t)b * IN_CAPS + (t + 1) * TILE_R + ir) * IN_D);
            const float4 ub = *reinterpret_cast<const float4*>(
                u + ((size_t)b * IN_CAPS + (t + 1) * TILE_R + ir) * IN_D + 4);
            unbuf[(t+1)&1][0]=ua.x; unbuf[(t+1)&1][1]=ua.y;
            unbuf[(t+1)&1][2]=ua.z; unbuf[(t+1)&1][3]=ua.w;
            unbuf[(t+1)&1][4]=ub.x; unbuf[(t+1)&1][5]=ub.y;
            unbuf[(t+1)&1][6]=ub.z; unbuf[(t+1)&1][7]=ub.w;
        }
        // compute uh[t][:] from tile[t&1]
        const uint32_t* trow = &tile[t & 1][ir * ROW_U32];
        #pragma unroll
        for (int k = 0; k < 8; ++k) uh[t][k] = 0.0f;
        #pragma unroll
        for (int n = 0; n < IN_D; ++n) {
            const uint4 rd = *reinterpret_cast<const uint4*>(
                &trow[((2 * n + mh) ^ sz) << 2]);
            const uint32_t dws[4] = {rd.x, rd.y, rd.z, rd.w};
            const float uv = unbuf[t & 1][n];
            #pragma unroll
            for (int kk = 0; kk < 4; ++kk) {
                const float wlo = __uint_as_float(dws[kk] << 16);
                const float whi = __uint_as_float(dws[kk] & 0xffff0000u);
                uh[t][2*kk]     = fmaf(uv, wlo, uh[t][2*kk]);
                uh[t][2*kk + 1] = fmaf(uv, whi, uh[t][2*kk + 1]);
            }
        }
        if (t < NTILE - 1) {
            #pragma unroll
            for (int q = 0; q < 8; ++q) {
                const int row = q * 24 + srow;
                uint32_t p0, p1;
                asm("v_cvt_pk_bf16_f32 %0, %1, %2" : "=v"(p0) : "v"(stg[q].x), "v"(stg[q].y));
                asm("v_cvt_pk_bf16_f32 %0, %1, %2" : "=v"(p1) : "v"(stg[q].z), "v"(stg[q].w));
                *reinterpret_cast<uint2*>(
                    &tile[(t+1) & 1][row * ROW_U32 + ((so ^ (row & 15)) << 2) + (sh << 1)]) =
                    make_uint2(p0, p1);
            }
        }
        __syncthreads();
    }

    // ---- routing iterations ----
    float blog[NTILE];
    #pragma unroll
    for (int r = 0; r < NTILE; ++r) blog[r] = 0.0f;
    float vv[8];
    const int grp = lane & 3;                // (mh<<1)|bl

    for (int it = 0; it < ITERS; ++it) {
        // softmax denominator over i for my b (iter 0: exp(0)=1 exactly;
        // logits stay small enough that max-subtraction is unnecessary)
        float e[NTILE];
        float esum = 0.0f;
        #pragma unroll
        for (int r = 0; r < NTILE; ++r) { e[r] = __expf(blog[r]); esum += e[r]; }
        #pragma unroll
        for (int msk = 4; msk <= 32; msk <<= 1) esum += __shfl_xor(esum, msk);
        if (lane < 4) red_s[wv * 4 + lane] = esum;
        __syncthreads();
        float gsum = 0.0f;
        #pragma unroll
        for (int q = 0; q < NW; ++q) gsum += red_s[q * 4 + grp];
        const float cinv = 1.0f / gsum;

        // s[k] (my m-half) = cinv * sum_i e_i * uh[i][k]
        float sp[8];
        #pragma unroll
        for (int k = 0; k < 8; ++k) sp[k] = 0.0f;
        #pragma unroll
        for (int r = 0; r < NTILE; ++r)
            #pragma unroll
            for (int k = 0; k < 8; ++k)
                sp[k] = fmaf(e[r], uh[r][k], sp[k]);
        #pragma unroll
        for (int msk = 4; msk <= 32; msk <<= 1)
            #pragma unroll
            for (int k = 0; k < 8; ++k)
                sp[k] += __shfl_xor(sp[k], msk);
        if (lane < 4) {
            #pragma unroll
            for (int k = 0; k < 8; ++k) red_m[(wv * 4 + lane) * 8 + k] = sp[k];
        }
        __syncthreads();
        float s2p = 0.0f;
        #pragma unroll
        for (int k = 0; k < 8; ++k) {
            float acc = 0.0f;
            #pragma unroll
            for (int q = 0; q < NW; ++q) acc += red_m[(q * 4 + grp) * 8 + k];
            const float sm = acc * cinv;
            vv[k] = sm;
            s2p = fmaf(sm, sm, s2p);
        }
        if (tid < 4) red_s2[tid] = s2p;      // tid<4 <=> wv==0 && ir==0
        __syncthreads();
        const float s2 = red_s2[bl] + red_s2[2 + bl];   // both m-halves
        const float scale = (s2 / (1.0f + s2)) * rsqrtf(s2 + 1e-8f);
        #pragma unroll
        for (int k = 0; k < 8; ++k) vv[k] *= scale;

        // logit update: a[r] = sum_m v[m]*uh[r][m]; partner (mask 2) holds
        // the other m-half for the same (b, i).
        if (it < ITERS - 1) {
            #pragma unroll
            for (int r = 0; r < NTILE; ++r) {
                float a = 0.0f;
                #pragma unroll
                for (int k = 0; k < 8; ++k) a = fmaf(vv[k], uh[r][k], a);
                a += __shfl_xor(a, 2);
                blog[r] += a;
            }
        }
    }

    // ---- write v[b0+bl, j, mh*8 .. mh*8+7] ----
    if (tid < 4) {
        float4* op = reinterpret_cast<float4*>(
            out + ((size_t)(b0 + bl) * OUT_CAPS + j) * OUT_D + mh * 8);
        op[0] = make_float4(vv[0], vv[1], vv[2], vv[3]);
        op[1] = make_float4(vv[4], vv[5], vv[6], vv[7]);
    }
}

extern "C" void kernel_launch(void* const* d_in, const int* in_sizes, int n_in,
                              void* d_out, int out_size, void* d_ws, size_t ws_size,
                              hipStream_t stream) {
    const float* u = (const float*)d_in[0];   // [128, 1152, 8]
    const float* w = (const float*)d_in[1];   // [1152, 32, 8, 16]
    float* out     = (float*)d_out;           // [128, 32, 16]
    (void)in_sizes; (void)n_in; (void)out_size; (void)d_ws; (void)ws_size;

    dim3 grid(OUT_CAPS * (B_SZ / G));   // 32 j x 64 batch-pairs = 2048 blocks
    dim3 block(THREADS);                // 768 threads = 12 waves
    hipLaunchKernelGGL(caps_route, grid, block, 0, stream, u, w, out);
}